// Round 10
// baseline (43.536 us; speedup 1.0000x reference)
//
#include <hip/hip_runtime.h>

// Conv2d 16->16, k=3, stride 1, pad 1, H=W=1024.
// Round 11: hardware-verified overlap -- asm-pinned prefetch spans compute.
//   R10 post-mortem: 2KB runs null at equal occupancy (page theory dead);
//   VGPR=60 shows the compiler AGAIN sank the prefetch into pack. Across
//   R1-R10 the one mechanism never realized on HW: loads outstanding while
//   MFMA runs (R6 pinned but drained immediately; R3/R4/R10 overlapped on
//   paper but compiler re-sunk). This round combines them on the R7 anchor:
//   NT=2 tiles/block, issue tile-1's 16 global_load_dwordx4 via asm
//   ("memory"-clobbered, outputs pinned = 64 VGPR) BEFORE compute(tile0),
//   drain with COUNTED s_waitcnt vmcnt(8) AFTER (8 output stores may stay
//   in flight; the 16 older loads retire), sched_barrier(0) per rule #18.
//   Weight loads ALSO via asm + one prologue vmcnt(0): otherwise the
//   compiler inserts its own vmcnt(<=4) before the first MFMA (counting
//   only ITS loads) and would force-retire 12/16 prefetches.
//   Geometry = R7 verbatim: TW=128, TH=4, 25KB LDS [y][x][ci] bf16 with
//   2-bit XOR swizzle, K=160 = 5 x mfma_f32_16x16x32_bf16, D[px][co] ->
//   float4 stores, prep-shuffled weights, grid-x = 8 = #XCDs.
//   launch_bounds(256,4): 4 blocks/CU (VGPR ~115), grid 1024 co-resident.

#define H 1024
#define W 1024
#define HW (H * W)
#define TW 128
#define TH 4
#define NT 2                 // tiles per block, stacked vertically
#define LROWS 6              // TH + 2 halo rows
#define NQ 34                // float4-quads per halo row
#define NJOBS (LROWS * NQ)   // 204 jobs (one per thread, tid<204)
#define LCOLS 130            // staged cols: lx in [0, 130)
#define LPITCH (LCOLS * 32)  // 4160 B (32 B per col = 16 ci * 2 B)
#define LDS_BYTES (LROWS * LPITCH)   // 24960

typedef __bf16 bf16x8 __attribute__((ext_vector_type(8)));
typedef float f32x4 __attribute__((ext_vector_type(4)));
typedef unsigned short ushort8 __attribute__((ext_vector_type(8)));
typedef unsigned int uint4v __attribute__((ext_vector_type(4)));

__device__ __host__ inline unsigned short f2bf(float f) {
  unsigned u = __builtin_bit_cast(unsigned, f);
  return (unsigned short)((u + 0x7fffu + ((u >> 16) & 1u)) >> 16);  // RNE
}

// wA[p*512 + lane*8 + j]: weight fragment, col=co=lane&15, k=(lane>>4)*8+j;
// mfma p covers taps {2p, 2p+1}; tap = 2p + (k>>4), ci = k&15.
__global__ __launch_bounds__(256) void conv_prep(const float* __restrict__ w,
                                                 unsigned short* __restrict__ wA) {
  int i = blockIdx.x * 256 + threadIdx.x;
  if (i >= 5 * 64 * 8) return;
  int j = i & 7;
  int l = (i >> 3) & 63;
  int p = i >> 9;
  int k = (l >> 4) * 8 + j;
  int t = 2 * p + (k >> 4);
  int ci = k & 15;
  int co = l & 15;
  float v = (t <= 8) ? w[co * 144 + ci * 9 + t] : 0.f;  // w[co][ci][ky][kx], t=ky*3+kx
  wA[i] = f2bf(v);
}

// 16 asm-pinned global_load_dwordx4: saddr = plane base (SGPR), voffset =
// per-thread pixel byte offset. "memory" clobber: no memory op crosses.
__device__ __forceinline__ void issue16(f32x4 (&L)[16],
                                        const float* __restrict__ x,
                                        unsigned voff) {
  asm volatile(
      "global_load_dwordx4 %0, %8, %9\n\t"
      "global_load_dwordx4 %1, %8, %10\n\t"
      "global_load_dwordx4 %2, %8, %11\n\t"
      "global_load_dwordx4 %3, %8, %12\n\t"
      "global_load_dwordx4 %4, %8, %13\n\t"
      "global_load_dwordx4 %5, %8, %14\n\t"
      "global_load_dwordx4 %6, %8, %15\n\t"
      "global_load_dwordx4 %7, %8, %16\n\t"
      : "=&v"(L[0]), "=&v"(L[1]), "=&v"(L[2]), "=&v"(L[3]),
        "=&v"(L[4]), "=&v"(L[5]), "=&v"(L[6]), "=&v"(L[7])
      : "v"(voff), "s"(x), "s"(x + HW), "s"(x + 2 * HW), "s"(x + 3 * HW),
        "s"(x + 4 * HW), "s"(x + 5 * HW), "s"(x + 6 * HW), "s"(x + 7 * HW)
      : "memory");
  asm volatile(
      "global_load_dwordx4 %0, %8, %9\n\t"
      "global_load_dwordx4 %1, %8, %10\n\t"
      "global_load_dwordx4 %2, %8, %11\n\t"
      "global_load_dwordx4 %3, %8, %12\n\t"
      "global_load_dwordx4 %4, %8, %13\n\t"
      "global_load_dwordx4 %5, %8, %14\n\t"
      "global_load_dwordx4 %6, %8, %15\n\t"
      "global_load_dwordx4 %7, %8, %16\n\t"
      : "=&v"(L[8]), "=&v"(L[9]), "=&v"(L[10]), "=&v"(L[11]),
        "=&v"(L[12]), "=&v"(L[13]), "=&v"(L[14]), "=&v"(L[15])
      : "v"(voff), "s"(x + 8 * HW), "s"(x + 9 * HW), "s"(x + 10 * HW),
        "s"(x + 11 * HW), "s"(x + 12 * HW), "s"(x + 13 * HW),
        "s"(x + 14 * HW), "s"(x + 15 * HW)
      : "memory");
}

// Pack 4 cols x 16 ci to LDS: fp32 pairs -> bf16x2, 8 x ds_write_b128.
__device__ __forceinline__ void pack16(const f32x4 (&L)[16], float rowm, int ly,
                                       int gx0, int colbase, char* lds) {
#pragma unroll
  for (int i = 0; i < 4; ++i) {
    const int gx = gx0 + i;
    const int lx = gx - (colbase - 1);
    if ((unsigned)lx < (unsigned)LCOLS) {
      const float fm = rowm * (((unsigned)gx < (unsigned)W) ? 1.f : 0.f);
      const int lb = (ly * LPITCH + lx * 32) ^ (((lx >> 2) & 3) << 4);
#pragma unroll
      for (int h = 0; h < 2; ++h) {
        uint4v d;
#pragma unroll
        for (int p = 0; p < 4; ++p) {
          const unsigned lo = f2bf(L[h * 8 + 2 * p][i] * fm);
          const unsigned hi = f2bf(L[h * 8 + 2 * p + 1][i] * fm);
          d[p] = lo | (hi << 16);
        }
        *(uint4v*)(lds + (lb ^ (h << 4))) = d;
      }
    }
  }
}

__global__ __launch_bounds__(256, 4) void conv_mfma(
    const float* __restrict__ x, const unsigned short* __restrict__ wA,
    float* __restrict__ out) {
  __shared__ __align__(16) char lds[LDS_BYTES];

  const int tid  = threadIdx.x;
  const int lane = tid & 63;
  const int wave = tid >> 6;
  const int m = lane & 15;   // A row = pixel within 16-px group; D col = co
  const int q = lane >> 4;   // k-quarter
  const int colbase  = blockIdx.x * TW;
  const int rowbase0 = blockIdx.y * (TH * NT);

  // ---- staging geometry (tile-invariant) ----
  const bool st = tid < NJOBS;
  int ly = 0, gx0 = 0, gx0c = 0;
  if (st) {
    ly = tid / NQ;                     // 0..5
    const int qx = tid - ly * NQ;      // 0..33
    gx0  = colbase - 4 + 4 * qx;
    gx0c = gx0 < 0 ? 0 : (gx0 > W - 4 ? W - 4 : gx0);
  }
  auto tile_off = [&](int rowbase, float& rm) -> unsigned {
    const int gy = rowbase - 1 + ly;
    rm = ((unsigned)gy < (unsigned)H) ? 1.f : 0.f;
    const int gyc = gy < 0 ? 0 : (gy > H - 1 ? H - 1 : gy);
    return (unsigned)((gyc * W + gx0c) * 4);
  };

  // ---- prologue: issue tile-0 loads + weight loads, ONE drain ----
  f32x4 L[16];
  float rowm;
  const unsigned voff0 = tile_off(rowbase0, rowm);
  if (st) issue16(L, x, voff0);

  // Weights via asm too: leaves the compiler with ZERO tracked VMEM, so it
  // never inserts its own vmcnt before the MFMAs (which would force-retire
  // the opaque prefetch loads).
  ushort8 wU[5];
  {
    const unsigned wvoff = (unsigned)(lane * 16);
    asm volatile(
        "global_load_dwordx4 %0, %5, %6\n\t"
        "global_load_dwordx4 %1, %5, %7\n\t"
        "global_load_dwordx4 %2, %5, %8\n\t"
        "global_load_dwordx4 %3, %5, %9\n\t"
        "global_load_dwordx4 %4, %5, %10\n\t"
        : "=&v"(wU[0]), "=&v"(wU[1]), "=&v"(wU[2]), "=&v"(wU[3]), "=&v"(wU[4])
        : "v"(wvoff), "s"(wA), "s"(wA + 512), "s"(wA + 1024), "s"(wA + 1536),
          "s"(wA + 2048)
        : "memory");
  }

  // ---- per-lane LDS read base addresses (wave owns row rowbase+wave) ----
  int baseaddr[5];
#pragma unroll
  for (int p = 0; p < 5; ++p) {
    int t = 2 * p + (q >> 1);
    int ky = 0, kx = 0;
    if (t <= 8) { ky = t / 3; kx = t - ky * 3; }  // t==9: valid addr, zero weights
    int col = m + kx;
    int b = ky * LPITCH + col * 32 + (q & 1) * 16;
    b ^= ((col >> 2) & 3) << 4;
    baseaddr[p] = b + wave * LPITCH;
  }

  asm volatile("s_waitcnt vmcnt(0)" ::: "memory");   // tile-0 + weights ready
  __builtin_amdgcn_sched_barrier(0);                 // rule #18
  if (st) pack16(L, rowm, ly, gx0, colbase, lds);
  asm volatile("s_waitcnt lgkmcnt(0)" ::: "memory");
  asm volatile("s_barrier" ::: "memory");

#define COMPUTE(RB)                                                         \
  {                                                                         \
    const int y = (RB) + wave;                                              \
    float* const orow = out + m * HW + y * W + colbase + q * 4;             \
    _Pragma("unroll") for (int g = 0; g < 8; ++g) {                         \
      f32x4 acc = {0.f, 0.f, 0.f, 0.f};                                     \
      _Pragma("unroll") for (int p = 0; p < 5; ++p) {                       \
        const ushort8 bU =                                                  \
            *(const ushort8*)(lds + (baseaddr[p] + g * 512));               \
        acc = __builtin_amdgcn_mfma_f32_16x16x32_bf16(                      \
            __builtin_bit_cast(bf16x8, bU),    /* A = pixels  */            \
            __builtin_bit_cast(bf16x8, wU[p]), /* B = weights */            \
            acc, 0, 0, 0);                                                  \
      }                                                                     \
      *(f32x4*)(orow + g * 16) = acc;                                       \
    }                                                                       \
  }

  // ---- pipelined pair: issue(1) | compute(0) | drain | pack(1) | compute(1)
  const unsigned voff1 = tile_off(rowbase0 + TH, rowm);
  if (st) issue16(L, x, voff1);        // 16 KB/wave in flight across compute
  COMPUTE(rowbase0);
  asm volatile("s_barrier" ::: "memory");            // all reads of buf done
  // Counted drain: 8 output stores (newer) may stay in flight; the 16
  // older prefetch loads must have retired once outstanding <= 8.
  asm volatile("s_waitcnt vmcnt(8)" ::: "memory");
  __builtin_amdgcn_sched_barrier(0);                 // rule #18
  if (st) pack16(L, rowm, ly, gx0, colbase, lds);
  asm volatile("s_waitcnt lgkmcnt(0)" ::: "memory");
  asm volatile("s_barrier" ::: "memory");
  COMPUTE(rowbase0 + TH);

#undef COMPUTE
}

extern "C" void kernel_launch(void* const* d_in, const int* in_sizes, int n_in,
                              void* d_out, int out_size, void* d_ws, size_t ws_size,
                              hipStream_t stream) {
  const float* x = (const float*)d_in[0];            // (1,16,1024,1024) fp32
  const float* w = (const float*)d_in[1];            // (16,16,3,3) fp32
  float* out = (float*)d_out;                        // (16,1024,1024) fp32
  unsigned short* wA = (unsigned short*)d_ws;        // 2560 ushorts = 5120 B

  conv_prep<<<10, 256, 0, stream>>>(w, wA);

  dim3 grid(W / TW, H / (TH * NT));                  // 8 x 128 = 1024 blocks
  conv_mfma<<<grid, 256, 0, stream>>>(x, wA, out);
}

// Round 11
// 37.478 us; speedup vs baseline: 1.1616x; 1.1616x over previous
//
#include <hip/hip_runtime.h>

// Conv2d 16->16, k=3, stride 1, pad 1, H=W=1024.
// FINAL (restores Round-7 artifact, 37.1us): TH=4/TW=128, 6 blocks/CU,
// asm-pinned 16-deep staging, one job per thread.
//
// Session conclusion (12 rounds): this dispatch is bound by the HBM
// pattern, not by schedule. Evidence ledger:
//   - bytes at floor: FETCH+WRITE ~= 119 MB (< naive 128 MB floor via
//     L2/LLC halo reuse); WRITE ~= 64 MB ideal.
//   - pattern BW ceiling ~3.4 TB/s: 11 structures (lockstep, syncthreads
//     pipeline, raw-barrier counted-vmcnt pipeline, asm-pinned ILP-16,
//     plane-major issue, 2KB-run row-band, nt-stores, 512-thr, NT=2/4)
//     all land 2.7-3.7 TB/s, while the harness's own fillBuffer does
//     6.7 TB/s pure-write at 8% occupancy on the same chip in-stream.
//     The difference: our mandatory 16-way plane-strided gather+scatter
//     (NCHW fp32 <-> ci-interleaved LDS transpose for MFMA).
//   - ILP null (R6: asm-proven 16-deep outstanding, flat), run length
//     null (R10: 2KB runs, flat), schedules null (R2-R4, R11), waves the
//     only positive lever, saturating ~40-50% occ (R7 = this kernel).
//   - compute side trivially overlapped: LDS ~7us, VALU ~5us, MFMA ~1us
//     per CU vs 37us wall.
//   time ~= 119 MB / 3.4 TB/s ~= 35us -> measured 37.1. Ceiling.
//
// Geometry: GEMM view D[px][co] = sum_k B[px][k]*A[k][co], k=tap*16+ci,
// 10 taps (tap 9 = zero pad) -> K=160 = 5 x mfma_f32_16x16x32_bf16.
// LDS [y][x][ci] bf16, 32 B/col, XOR swizzle ((col>>2)&3)<<4 on byte bits
// 4-5 (write side folded into lb, read side folded into baseaddr).
// Weights pre-shuffled into fragment layout by conv_prep (A-operand:
// col=co=lane&15, k=(lane>>4)*8+j). D: col=lane&15=c_out, row=q*4+j=pixel
// -> each lane stores 4 consecutive pixels of one plane as one float4.

#define H 1024
#define W 1024
#define HW (H * W)
#define TW 128
#define TH 4
#define LROWS 6              // TH + 2 halo rows
#define NQ 34                // float4-quads per halo row ([colbase-4, colbase+132))
#define NJOBS (LROWS * NQ)   // 204  (<= 256: one job per thread)
#define LCOLS 130            // staged cols: lx in [0, 130)
#define LPITCH (LCOLS * 32)  // 4160 B (32 B per col = 16 ci * 2 B)
#define LDS_BYTES (LROWS * LPITCH)   // 24960 -> 6 blocks/CU = 24 waves

typedef __bf16 bf16x8 __attribute__((ext_vector_type(8)));
typedef float f32x4 __attribute__((ext_vector_type(4)));
typedef unsigned short ushort8 __attribute__((ext_vector_type(8)));
typedef unsigned int uint4v __attribute__((ext_vector_type(4)));

__device__ __host__ inline unsigned short f2bf(float f) {
  unsigned u = __builtin_bit_cast(unsigned, f);
  return (unsigned short)((u + 0x7fffu + ((u >> 16) & 1u)) >> 16);  // RNE
}

// wA[p*512 + lane*8 + j]: weight fragment, col=co=lane&15, k=(lane>>4)*8+j;
// mfma p covers taps {2p, 2p+1}; tap = 2p + (k>>4), ci = k&15.
__global__ __launch_bounds__(256) void conv_prep(const float* __restrict__ w,
                                                 unsigned short* __restrict__ wA) {
  int i = blockIdx.x * 256 + threadIdx.x;
  if (i >= 5 * 64 * 8) return;
  int j = i & 7;
  int l = (i >> 3) & 63;
  int p = i >> 9;
  int k = (l >> 4) * 8 + j;
  int t = 2 * p + (k >> 4);
  int ci = k & 15;
  int co = l & 15;
  float v = (t <= 8) ? w[co * 144 + ci * 9 + t] : 0.f;  // w[co][ci][ky][kx], t=ky*3+kx
  wA[i] = f2bf(v);
}

// One staging job: 4 cols x 16 channels. 16 asm-pinned global_load_dwordx4
// (saddr = uniform plane base, voffset = per-thread pixel), single drain,
// pack fp32->bf16 pairs, 8 x ds_write_b128.
__device__ __forceinline__ void stage_job(int j, const float* __restrict__ x,
                                          int colbase, int rowbase, char* lds) {
  const int ly  = j / NQ;            // 0..LROWS-1
  const int qx  = j - ly * NQ;       // 0..33
  const int gy  = rowbase - 1 + ly;
  const float rowm = ((unsigned)gy < (unsigned)H) ? 1.f : 0.f;
  const int gyc  = gy < 0 ? 0 : (gy > H - 1 ? H - 1 : gy);
  const int gx0  = colbase - 4 + 4 * qx;
  const int gx0c = gx0 < 0 ? 0 : (gx0 > W - 4 ? W - 4 : gx0);
  const unsigned voff = (unsigned)((gyc * W + gx0c) * 4);  // bytes, ci-invariant

  f32x4 L[16];
  asm volatile(
      "global_load_dwordx4 %0, %8, %9\n\t"
      "global_load_dwordx4 %1, %8, %10\n\t"
      "global_load_dwordx4 %2, %8, %11\n\t"
      "global_load_dwordx4 %3, %8, %12\n\t"
      "global_load_dwordx4 %4, %8, %13\n\t"
      "global_load_dwordx4 %5, %8, %14\n\t"
      "global_load_dwordx4 %6, %8, %15\n\t"
      "global_load_dwordx4 %7, %8, %16\n\t"
      : "=&v"(L[0]), "=&v"(L[1]), "=&v"(L[2]), "=&v"(L[3]),
        "=&v"(L[4]), "=&v"(L[5]), "=&v"(L[6]), "=&v"(L[7])
      : "v"(voff), "s"(x), "s"(x + HW), "s"(x + 2 * HW), "s"(x + 3 * HW),
        "s"(x + 4 * HW), "s"(x + 5 * HW), "s"(x + 6 * HW), "s"(x + 7 * HW));
  asm volatile(
      "global_load_dwordx4 %0, %8, %9\n\t"
      "global_load_dwordx4 %1, %8, %10\n\t"
      "global_load_dwordx4 %2, %8, %11\n\t"
      "global_load_dwordx4 %3, %8, %12\n\t"
      "global_load_dwordx4 %4, %8, %13\n\t"
      "global_load_dwordx4 %5, %8, %14\n\t"
      "global_load_dwordx4 %6, %8, %15\n\t"
      "global_load_dwordx4 %7, %8, %16\n\t"
      : "=&v"(L[8]), "=&v"(L[9]), "=&v"(L[10]), "=&v"(L[11]),
        "=&v"(L[12]), "=&v"(L[13]), "=&v"(L[14]), "=&v"(L[15])
      : "v"(voff), "s"(x + 8 * HW), "s"(x + 9 * HW), "s"(x + 10 * HW),
        "s"(x + 11 * HW), "s"(x + 12 * HW), "s"(x + 13 * HW),
        "s"(x + 14 * HW), "s"(x + 15 * HW));

  // All 16 loads in flight; drain once; fence VALU reordering (rule #18).
  asm volatile("s_waitcnt vmcnt(0)" ::: "memory");
  __builtin_amdgcn_sched_barrier(0);

#pragma unroll
  for (int i = 0; i < 4; ++i) {
    const int gx = gx0 + i;
    const int lx = gx - (colbase - 1);
    if ((unsigned)lx < (unsigned)LCOLS) {
      const float fm = rowm * (((unsigned)gx < (unsigned)W) ? 1.f : 0.f);
      const int lb = (ly * LPITCH + lx * 32) ^ (((lx >> 2) & 3) << 4);
#pragma unroll
      for (int h = 0; h < 2; ++h) {
        uint4v d;
#pragma unroll
        for (int p = 0; p < 4; ++p) {
          const unsigned lo = f2bf(L[h * 8 + 2 * p][i] * fm);
          const unsigned hi = f2bf(L[h * 8 + 2 * p + 1][i] * fm);
          d[p] = lo | (hi << 16);
        }
        *(uint4v*)(lds + (lb ^ (h << 4))) = d;
      }
    }
  }
}

__global__ __launch_bounds__(256, 6) void conv_mfma(
    const float* __restrict__ x, const unsigned short* __restrict__ wA,
    float* __restrict__ out) {
  __shared__ __align__(16) char lds[LDS_BYTES];

  const int tid  = threadIdx.x;
  const int lane = tid & 63;
  const int wave = tid >> 6;
  const int m = lane & 15;   // A row = pixel within 16-px group
  const int q = lane >> 4;   // k-quarter
  const int colbase = blockIdx.x * TW;
  const int rowbase = blockIdx.y * TH;

  // ---- stage: one job per thread (204 jobs) ----
  if (tid < NJOBS) stage_job(tid, x, colbase, rowbase, lds);

  // ---- weight fragments: 5 x 16B uniform cached loads ----
  ushort8 wU[5];
#pragma unroll
  for (int p = 0; p < 5; ++p)
    wU[p] = *(const ushort8*)&wA[(p * 64 + lane) * 8];

  // ---- per-lane LDS read base addresses (wave owns one output row) ----
  int baseaddr[5];
#pragma unroll
  for (int p = 0; p < 5; ++p) {
    int t = 2 * p + (q >> 1);
    int ky = 0, kx = 0;
    if (t <= 8) { ky = t / 3; kx = t - ky * 3; }  // t==9: valid addr, zero weights
    int col = m + kx;
    int b = ky * LPITCH + col * 32 + (q & 1) * 16;
    b ^= ((col >> 2) & 3) << 4;
    baseaddr[p] = b + wave * LPITCH;
  }

  __syncthreads();

  // ---- compute: wave -> row (rowbase+wave), 8 groups of 16 px ----
#pragma unroll
  for (int g = 0; g < 8; ++g) {
    f32x4 acc = {0.f, 0.f, 0.f, 0.f};
#pragma unroll
    for (int p = 0; p < 5; ++p) {
      ushort8 bU = *(const ushort8*)(lds + (baseaddr[p] + g * 512));
      acc = __builtin_amdgcn_mfma_f32_16x16x32_bf16(
          __builtin_bit_cast(bf16x8, bU),       // A = pixels
          __builtin_bit_cast(bf16x8, wU[p]),    // B = weights
          acc, 0, 0, 0);
    }
    // D: col = lane&15 = c_out, row = q*4+j = pixel -> float4 store of 4
    // consecutive pixels for one channel.
    const int y  = rowbase + wave;
    const int x0 = colbase + g * 16 + q * 4;
    *(f32x4*)(out + m * HW + y * W + x0) = acc;
  }
}

extern "C" void kernel_launch(void* const* d_in, const int* in_sizes, int n_in,
                              void* d_out, int out_size, void* d_ws, size_t ws_size,
                              hipStream_t stream) {
  const float* x = (const float*)d_in[0];            // (1,16,1024,1024) fp32
  const float* w = (const float*)d_in[1];            // (16,16,3,3) fp32
  float* out = (float*)d_out;                        // (16,1024,1024) fp32
  unsigned short* wA = (unsigned short*)d_ws;        // 2560 ushorts = 5120 B

  conv_prep<<<10, 256, 0, stream>>>(w, wA);

  dim3 grid(W / TW, H / TH);                         // 8 x 256 = 2048 blocks
  conv_mfma<<<grid, 256, 0, stream>>>(x, wA, out);
}

// Round 12
// 36.852 us; speedup vs baseline: 1.1813x; 1.0170x over previous
//
#include <hip/hip_runtime.h>

// Conv2d 16->16, k=3, stride 1, pad 1, H=W=1024.
// Round 13: TH=16 mega-block -- 32 waves/CU + 1.125x halo ratio.
//   R12 (R7 restore) reproduced 37.5us, confirming the ~3.4 TB/s pattern
//   model. Ledger audit: the only BW-positive lever (waves/CU: 7->24 gave
//   2.8->3.5 TB/s) and the only dur-positive byte lever (halo ratio, R5)
//   were never pushed together. TH=16, 1024-thread blocks: LDS = 18 rows
//   x 4160 B = 74.9 KB -> 2 blocks/CU = 32 waves/CU (100% nominal, vs
//   R7's 24), halo 18/16 = 1.125x -> FETCH ~45 MB (vs 53). Constraint:
//   VGPR <= 64 for 8 waves/EU -- staging uses R2's register-lean two-half
//   scheme (8 planes live, VGPR 36 measured there; asm pinning dropped,
//   R6 proved neutral), __launch_bounds__(1024,8) caps the allocator.
//   Tell: VGPR<=64 & no scratch. Kill: dur>=36us -> declare roofline.
//   Geometry otherwise R7 verbatim: TW=128, LDS [y][x][ci] bf16, 32 B/col,
//   XOR swizzle ((col>>2)&3)<<4 on byte bits 4-5, K=160 = 5 x
//   mfma_f32_16x16x32_bf16, D[px][co] -> float4 stores (4 consecutive
//   pixels of one plane per lane), prep-shuffled weights, grid-x = 8 =
//   #XCDs (column->XCD affinity for halo L2 reuse).

#define H 1024
#define W 1024
#define HW (H * W)
#define TW 128
#define TH 16
#define LROWS 18             // TH + 2 halo rows
#define NQ 34                // float4-quads per halo row ([colbase-4, colbase+132))
#define NJOBS (LROWS * NQ)   // 612  (<= 1024: one job per thread)
#define LCOLS 130            // staged cols: lx in [0, 130)
#define LPITCH (LCOLS * 32)  // 4160 B (32 B per col = 16 ci * 2 B)
#define LDS_BYTES (LROWS * LPITCH)   // 74880 -> 2 blocks/CU = 32 waves

typedef __bf16 bf16x8 __attribute__((ext_vector_type(8)));
typedef float f32x4 __attribute__((ext_vector_type(4)));
typedef unsigned short ushort8 __attribute__((ext_vector_type(8)));
typedef unsigned int uint4v __attribute__((ext_vector_type(4)));

__device__ __host__ inline unsigned short f2bf(float f) {
  unsigned u = __builtin_bit_cast(unsigned, f);
  return (unsigned short)((u + 0x7fffu + ((u >> 16) & 1u)) >> 16);  // RNE
}

// wA[p*512 + lane*8 + j]: weight fragment, col=co=lane&15, k=(lane>>4)*8+j;
// mfma p covers taps {2p, 2p+1}; tap = 2p + (k>>4), ci = k&15.
__global__ __launch_bounds__(256) void conv_prep(const float* __restrict__ w,
                                                 unsigned short* __restrict__ wA) {
  int i = blockIdx.x * 256 + threadIdx.x;
  if (i >= 5 * 64 * 8) return;
  int j = i & 7;
  int l = (i >> 3) & 63;
  int p = i >> 9;
  int k = (l >> 4) * 8 + j;
  int t = 2 * p + (k >> 4);
  int ci = k & 15;
  int co = l & 15;
  float v = (t <= 8) ? w[co * 144 + ci * 9 + t] : 0.f;  // w[co][ci][ky][kx], t=ky*3+kx
  wA[i] = f2bf(v);
}

__global__ __launch_bounds__(1024, 8) void conv_mfma(
    const float* __restrict__ x, const unsigned short* __restrict__ wA,
    float* __restrict__ out) {
  __shared__ __align__(16) char lds[LDS_BYTES];

  const int tid  = threadIdx.x;
  const int lane = tid & 63;
  const int wave = tid >> 6;           // 0..15
  const int m = lane & 15;   // A row = pixel within 16-px group; D col = co
  const int q = lane >> 4;   // k-quarter
  const int colbase = blockIdx.x * TW;
  const int rowbase = blockIdx.y * TH;

  // ---- stage: one job per thread (612 jobs = 4 cols x 16 channels) ----
  // Register-lean two-half scheme (R2-proven, VGPR ~36): 8 planes live at
  // a time; per half h, per col i: one 16-B ds_write covering 8 ci.
  if (tid < NJOBS) {
    const int ly  = tid / NQ;          // 0..17
    const int qx  = tid - ly * NQ;     // 0..33
    const int gy  = rowbase - 1 + ly;
    const float rowm = ((unsigned)gy < (unsigned)H) ? 1.f : 0.f;
    const int gyc  = gy < 0 ? 0 : (gy > H - 1 ? H - 1 : gy);
    const int gx0  = colbase - 4 + 4 * qx;
    const int gx0c = gx0 < 0 ? 0 : (gx0 > W - 4 ? W - 4 : gx0);
    const float* xb = x + gyc * W + gx0c;   // always valid, 16-B aligned

    float fm[4];
    int lok[4], lb[4];
#pragma unroll
    for (int i = 0; i < 4; ++i) {
      const int gx = gx0 + i;
      fm[i] = rowm * (((unsigned)gx < (unsigned)W) ? 1.f : 0.f);
      const int lx = gx - (colbase - 1);
      lok[i] = (unsigned)lx < (unsigned)LCOLS;
      lb[i]  = (ly * LPITCH + lx * 32) ^ (((lx >> 2) & 3) << 4);
    }
#pragma unroll
    for (int h = 0; h < 2; ++h) {
      f32x4 L[8];
#pragma unroll
      for (int c = 0; c < 8; ++c)
        L[c] = *(const f32x4*)(xb + (h * 8 + c) * HW);
#pragma unroll
      for (int i = 0; i < 4; ++i) {
        if (lok[i]) {
          uint4v d;
#pragma unroll
          for (int p = 0; p < 4; ++p) {
            const unsigned lo = f2bf(L[2 * p][i] * fm[i]);
            const unsigned hi = f2bf(L[2 * p + 1][i] * fm[i]);
            d[p] = lo | (hi << 16);
          }
          *(uint4v*)(lds + (lb[i] ^ (h << 4))) = d;
        }
      }
    }
  }

  // ---- weight fragments: 5 x 16B uniform cached loads ----
  ushort8 wU[5];
#pragma unroll
  for (int p = 0; p < 5; ++p)
    wU[p] = *(const ushort8*)&wA[(p * 64 + lane) * 8];

  // ---- per-lane LDS read base addresses (wave owns row rowbase+wave) ----
  int baseaddr[5];
#pragma unroll
  for (int p = 0; p < 5; ++p) {
    int t = 2 * p + (q >> 1);
    int ky = 0, kx = 0;
    if (t <= 8) { ky = t / 3; kx = t - ky * 3; }  // t==9: valid addr, zero weights
    int col = m + kx;
    int b = ky * LPITCH + col * 32 + (q & 1) * 16;
    b ^= ((col >> 2) & 3) << 4;
    baseaddr[p] = b + wave * LPITCH;   // wave*LPITCH has no bits <6: swizzle-safe
  }

  __syncthreads();

  // ---- compute: wave -> row (rowbase+wave), 8 groups of 16 px ----
#pragma unroll
  for (int g = 0; g < 8; ++g) {
    f32x4 acc = {0.f, 0.f, 0.f, 0.f};
#pragma unroll
    for (int p = 0; p < 5; ++p) {
      ushort8 bU = *(const ushort8*)(lds + (baseaddr[p] + g * 512));
      acc = __builtin_amdgcn_mfma_f32_16x16x32_bf16(
          __builtin_bit_cast(bf16x8, bU),       // A = pixels
          __builtin_bit_cast(bf16x8, wU[p]),    // B = weights
          acc, 0, 0, 0);
    }
    // D: col = lane&15 = c_out, row = q*4+j = pixel -> float4 store of 4
    // consecutive pixels for one channel.
    const int y  = rowbase + wave;
    const int x0 = colbase + g * 16 + q * 4;
    *(f32x4*)(out + m * HW + y * W + x0) = acc;
  }
}

extern "C" void kernel_launch(void* const* d_in, const int* in_sizes, int n_in,
                              void* d_out, int out_size, void* d_ws, size_t ws_size,
                              hipStream_t stream) {
  const float* x = (const float*)d_in[0];            // (1,16,1024,1024) fp32
  const float* w = (const float*)d_in[1];            // (16,16,3,3) fp32
  float* out = (float*)d_out;                        // (16,1024,1024) fp32
  unsigned short* wA = (unsigned short*)d_ws;        // 2560 ushorts = 5120 B

  conv_prep<<<10, 256, 0, stream>>>(w, wA);

  dim3 grid(W / TW, H / TH);                         // 8 x 64 = 512 blocks
  conv_mfma<<<grid, 1024, 0, stream>>>(x, wA, out);
}